// Round 1
// baseline (180.338 us; speedup 1.0000x reference)
//
#include <hip/hip_runtime.h>
#include <math.h>

#define HW_   128
#define CIN_  64
#define IMG_  (HW_ * HW_)       // 16384

#define TR_    5                // tile rows  [h-2 .. h+2]
#define TC_    72               // tile cols  [w0-4 .. w0+67]
#define PIT_   35               // dwords per pixel (64ch bf16 = 32 dw + 3 pad)
                                // 35: per-pixel bank stride 3 (coprime 32) -> conflict-lite
#define TILEDW (TR_ * TC_ * PIT_)   // 12600 dw = 50400 B

typedef short    s16x8 __attribute__((ext_vector_type(8)));
typedef float    f32x4 __attribute__((ext_vector_type(4)));
typedef unsigned u32x4 __attribute__((ext_vector_type(4)));

__device__ __forceinline__ short f2bf(float f) {
  union { float f; unsigned i; } v; v.f = f;
  unsigned r = (v.i + 0x7fffu + ((v.i >> 16) & 1u)) >> 16;   // RNE
  return (short)r;
}

#if defined(__has_builtin)
#if __has_builtin(__builtin_amdgcn_cvt_pk_bf16_f32)
#define HAVE_CVT_PK_BF16 1
#endif
#endif

// pack two f32 -> bf16 pair (lo=a, hi=b)
__device__ __forceinline__ unsigned PK2(float a, float b) {
#ifdef HAVE_CVT_PK_BF16
  typedef __bf16 bf16x2_t __attribute__((ext_vector_type(2)));
  union { bf16x2_t v; unsigned u; } cv;
  cv.v = __builtin_amdgcn_cvt_pk_bf16_f32(a, b);
  return cv.u;
#else
  union { float f; unsigned u; } ua, ub; ua.f = a; ub.f = b;
  unsigned ra = ua.u + 0x7fffu + ((ua.u >> 16) & 1u);
  unsigned rb = ub.u + 0x7fffu + ((ub.u >> 16) & 1u);
  return __builtin_amdgcn_perm(rb, ra, 0x07060302u);
#endif
}

// lo channel of packed pair, exact
__device__ __forceinline__ float bfl(unsigned d) {
  union { unsigned u; float f; } v; v.u = d << 16; return v.f;
}
// hi channel, "dirty": low 16 mantissa bits are junk (rel err ~2^-16,
// far below the 2^-9 bf16 repack rounding) -- saves the v_and per dword
__device__ __forceinline__ float bfh(unsigned d) {
  union { unsigned u; float f; } v; v.u = d; return v.f;
}

// ws layout (bytes):
//   [0,     36864)  wOf bf16 [j:9][ks:2][q:4][m:32][i:8]  (A-frag order, m>=27 zero)
//   [36864, 110592) wA  bf16 [j:9][ks:2][q:4][o:64][i:8]  (A-frag order)

__global__ __launch_bounds__(256) void wprep(const float* __restrict__ w_off,
                                             const float* __restrict__ w_conv,
                                             short* __restrict__ wOf,
                                             short* __restrict__ wA) {
  int t = blockIdx.x * 256 + threadIdx.x;
  if (t < 36864) {
    int i = t & 7, o = (t >> 3) & 63, q = (t >> 9) & 3, ks = (t >> 11) & 1, j = t >> 12;
    int c = ks * 32 + q * 8 + i;
    wA[t] = f2bf(w_conv[o * 576 + c * 9 + j]);
  }
  if (t < 18432) {
    int i = t & 7, m = (t >> 3) & 31, q = (t >> 8) & 3, ks = (t >> 10) & 1, j = t >> 11;
    int c = ks * 32 + q * 8 + i;
    wOf[t] = (m < 27) ? f2bf(w_off[(m * 64 + c) * 9 + j]) : (short)0;
  }
}

// Fully fused: stage f32 NCHW -> bf16 NHWC halo tile in LDS (zero-filled OOB,
// one barrier), offset conv (MFMA from tile, no masking needed),
// shuffle-exchange offsets (no barrier),
// LDS-gather deformable sampling + MFMA GEMM (global fallback for |o|>=1).
__global__ __launch_bounds__(256)
__attribute__((amdgpu_waves_per_eu(3)))
void dfuse(const float* __restrict__ x,
           const short* __restrict__ wOf,
           const float* __restrict__ b_off,
           const short* __restrict__ wA,
           float* __restrict__ out) {
  __shared__ __align__(16) unsigned lds_[TILEDW];

  int bi  = blockIdx.x >> 8;
  int hw0 = (blockIdx.x & 255) * 64;
  int h   = hw0 >> 7;
  int w0  = hw0 & 127;
  int t   = threadIdx.x;
  int wv  = t >> 6, l = t & 63;
  int col = l & 15, q = l >> 4;
  int px_local = wv * 16 + col;
  int p = hw0 + px_local;
  int w = w0 + px_local;

  const float* xB = x + (size_t)bi * (CIN_ * IMG_);

  // ---- stage halo tile: rows h-2..h+2, cols w0-4..w0+67, 64 ch bf16 ----
  // unit = (row r, ch-pair cp, col-chunk cc of 4 px); cc fastest => coalesced.
  // OOB image positions are stored as ZERO (conv zero-padding + safe garbage-free
  // reads in phase 3). xg0 is 4-aligned and HW_%4==0 => per-unit-uniform mask.
  for (int u = t; u < TR_ * 32 * 18; u += 256) {     // 2880 units
    int cc = u % 18;
    int rc = u / 18;
    int cp = rc & 31;
    int r  = rc >> 5;
    int y  = h - 2 + r;
    int ys = min(max(y, 0), HW_ - 1);
    int xg0 = w0 - 4 + cc * 4;
    int xs  = min(max(xg0, 0), HW_ - 4);             // stays 16B-aligned
    bool ok = (y >= 0) && (y < HW_) && (xg0 >= 0) && (xg0 < HW_);
    const float* s0 = xB + (2 * cp) * IMG_ + ys * HW_ + xs;
    float4 f0 = *(const float4*)s0;                  // ch 2cp
    float4 f1 = *(const float4*)(s0 + IMG_);         // ch 2cp+1
    int sd = (r * TC_ + cc * 4) * PIT_ + cp;
    lds_[sd]            = ok ? PK2(f0.x, f1.x) : 0u;
    lds_[sd + PIT_]     = ok ? PK2(f0.y, f1.y) : 0u;
    lds_[sd + 2 * PIT_] = ok ? PK2(f0.z, f1.z) : 0u;
    lds_[sd + 3 * PIT_] = ok ? PK2(f0.w, f1.w) : 0u;
  }
  __syncthreads();

  // ---- phase 1: offset conv from tile (tile is zero-padded: no masking) ----
  float oall[32];
  {
    const short* wq = wOf + q * 256 + col * 8;
    f32x4 a0v = {0.f, 0.f, 0.f, 0.f};
    f32x4 a1v = {0.f, 0.f, 0.f, 0.f};
    const unsigned* tb = &lds_[(px_local + 4) * PIT_ + q * 4];
#pragma unroll
    for (int j = 0; j < 9; ++j) {
      int dy = j / 3 - 1, dx = j % 3 - 1;
      const unsigned* tp = tb + ((dy + 2) * TC_ + dx) * PIT_;   // imm offsets
      union { u32x4 u; s16x8 v; } B0, B1;
      B0.u = *(const u32x4*)tp;
      B1.u = *(const u32x4*)(tp + 16);
      const short* wj = wq + j * 2048;
      s16x8 a00 = *(const s16x8*)(wj);
      s16x8 a01 = *(const s16x8*)(wj + 128);
      s16x8 a10 = *(const s16x8*)(wj + 1024);
      s16x8 a11 = *(const s16x8*)(wj + 1024 + 128);
      a0v = __builtin_amdgcn_mfma_f32_16x16x32_bf16(a00, B0.v, a0v, 0, 0, 0);
      a1v = __builtin_amdgcn_mfma_f32_16x16x32_bf16(a01, B0.v, a1v, 0, 0, 0);
      a0v = __builtin_amdgcn_mfma_f32_16x16x32_bf16(a10, B1.v, a0v, 0, 0, 0);
      a1v = __builtin_amdgcn_mfma_f32_16x16x32_bf16(a11, B1.v, a1v, 0, 0, 0);
    }
    // bias + sigmoid by producer lanes, then wave-local shuffle exchange
    float myv[8];
#pragma unroll
    for (int r = 0; r < 4; ++r) myv[r] = a0v[r] + b_off[q * 4 + r];
#pragma unroll
    for (int r = 0; r < 4; ++r) {
      int ch = 16 + q * 4 + r;
      float bo = b_off[min(ch, 26)];
      float v = a1v[r] + bo;
      myv[4 + r] = (ch >= 18) ? (1.f / (1.f + __expf(-v))) : v;
    }
#pragma unroll
    for (int qq = 0; qq < 4; ++qq) {
      int src = qq * 16 + col;
#pragma unroll
      for (int r = 0; r < 4; ++r) {
        oall[qq * 4 + r]      = __shfl(myv[r], src);
        oall[16 + qq * 4 + r] = __shfl(myv[4 + r], src);
      }
    }
  }

  // ---- phase 3: LDS-gather sampling + MFMA GEMM ----
  f32x4 acc[4];
#pragma unroll
  for (int ms = 0; ms < 4; ++ms) acc[ms] = (f32x4){0.f, 0.f, 0.f, 0.f};

  const short* wqA = wA + q * 512 + col * 8;

#pragma unroll
  for (int j = 0; j < 9; ++j) {
    float o1 = oall[j], o2 = oall[9 + j], mk = oall[18 + j];

    float pxf = o1 + (float)(w + (j % 3) - 1);
    float pyf = o2 + (float)(h + (j / 3) - 1);
    float fx = floorf(pxf), fy = floorf(pyf);
    int   x0 = (int)fx,   y0 = (int)fy;
    float ax = pxf - fx, ay = pyf - fy;
    float bx = 1.f - ax, by = 1.f - ay;

    // validity factorizes per-axis: zero the axis weight instead of the product
    bx = (x0 >= 0  && x0 < HW_)     ? bx : 0.f;
    ax = (x0 >= -1 && x0 < HW_ - 1) ? ax : 0.f;
    by = (y0 >= 0  && y0 < HW_)     ? by : 0.f;
    ay = (y0 >= -1 && y0 < HW_ - 1) ? ay : 0.f;
    float bym = by * mk, aym = ay * mk;
    float u00 = bym * bx, u01 = bym * ax;
    float u10 = aym * bx, u11 = aym * ax;

    unsigned F0u[4], F1u[4];
    bool intile = (o1 >= -1.f) && (o1 < 1.f) && (o2 >= -1.f) && (o2 < 1.f);
    if (intile) {
      // in-tile guarantee: r0 in [0,3], c0 in [2,68] -> no clamps, r1=r0+1,
      // c1=c0+1 -> all 8 reads are one base + compile-time immediates
      int r0 = y0 - (h - 2), c0 = x0 - (w0 - 4);
      const unsigned* t00 = &lds_[(r0 * TC_ + c0) * PIT_ + q * 4];
      u32x4 A00 = *(const u32x4*)(t00);
      u32x4 A01 = *(const u32x4*)(t00 + PIT_);
      u32x4 A10 = *(const u32x4*)(t00 + TC_ * PIT_);
      u32x4 A11 = *(const u32x4*)(t00 + TC_ * PIT_ + PIT_);
      u32x4 B00 = *(const u32x4*)(t00 + 16);
      u32x4 B01 = *(const u32x4*)(t00 + PIT_ + 16);
      u32x4 B10 = *(const u32x4*)(t00 + TC_ * PIT_ + 16);
      u32x4 B11 = *(const u32x4*)(t00 + TC_ * PIT_ + PIT_ + 16);
#pragma unroll
      for (int i = 0; i < 4; ++i) {
        float vlo = fmaf(bfl(A00[i]), u00, fmaf(bfl(A01[i]), u01,
                    fmaf(bfl(A10[i]), u10, bfl(A11[i]) * u11)));
        float vhi = fmaf(bfh(A00[i]), u00, fmaf(bfh(A01[i]), u01,
                    fmaf(bfh(A10[i]), u10, bfh(A11[i]) * u11)));
        F0u[i] = PK2(vlo, vhi);
        float wlo = fmaf(bfl(B00[i]), u00, fmaf(bfl(B01[i]), u01,
                    fmaf(bfl(B10[i]), u10, bfl(B11[i]) * u11)));
        float whi = fmaf(bfh(B00[i]), u00, fmaf(bfh(B01[i]), u01,
                    fmaf(bfh(B10[i]), u10, bfh(B11[i]) * u11)));
        F1u[i] = PK2(wlo, whi);
      }
    } else {
      // rare fallback: gather straight from f32 NCHW x (clamps only here)
      int xc0 = min(max(x0, 0), HW_ - 1), xc1 = min(max(x0 + 1, 0), HW_ - 1);
      int yc0 = min(max(y0, 0), HW_ - 1), yc1 = min(max(y0 + 1, 0), HW_ - 1);
      int g00 = yc0 * HW_ + xc0, g01 = yc0 * HW_ + xc1;
      int g10 = yc1 * HW_ + xc0, g11 = yc1 * HW_ + xc1;
      for (int hB = 0; hB < 2; ++hB) {
        for (int ii = 0; ii < 4; ++ii) {
          int c0i = hB * 32 + q * 8 + 2 * ii;
          const float* pc = xB + c0i * IMG_;
          const float* pd = pc + IMG_;
          float va = u00 * pc[g00] + u01 * pc[g01] + u10 * pc[g10] + u11 * pc[g11];
          float vb = u00 * pd[g00] + u01 * pd[g01] + u10 * pd[g10] + u11 * pd[g11];
          if (hB) F1u[ii] = PK2(va, vb); else F0u[ii] = PK2(va, vb);
        }
      }
    }

    union { unsigned u[4]; s16x8 v; } F0, F1;
#pragma unroll
    for (int i = 0; i < 4; ++i) { F0.u[i] = F0u[i]; F1.u[i] = F1u[i]; }

    const short* wj = wqA + j * 4096;
#pragma unroll
    for (int ms = 0; ms < 4; ++ms) {
      s16x8 a0 = *(const s16x8*)(wj + ms * 128);
      acc[ms] = __builtin_amdgcn_mfma_f32_16x16x32_bf16(a0, F0.v, acc[ms], 0, 0, 0);
    }
#pragma unroll
    for (int ms = 0; ms < 4; ++ms) {
      s16x8 a1 = *(const s16x8*)(wj + 2048 + ms * 128);
      acc[ms] = __builtin_amdgcn_mfma_f32_16x16x32_bf16(a1, F1.v, acc[ms], 0, 0, 0);
    }
  }

  float* op = out + (size_t)bi * (CIN_ * IMG_) + p;
#pragma unroll
  for (int ms = 0; ms < 4; ++ms)
#pragma unroll
    for (int r = 0; r < 4; ++r)
      op[(ms * 16 + q * 4 + r) * IMG_] = acc[ms][r];
}

extern "C" void kernel_launch(void* const* d_in, const int* in_sizes, int n_in,
                              void* d_out, int out_size, void* d_ws, size_t ws_size,
                              hipStream_t stream) {
  const float* x      = (const float*)d_in[0];
  const float* w_off  = (const float*)d_in[1];
  const float* b_off  = (const float*)d_in[2];
  const float* w_conv = (const float*)d_in[3];
  float* out = (float*)d_out;

  char* ws = (char*)d_ws;
  short* wOf = (short*)(ws);
  short* wA  = (short*)(ws + 36864);

  hipLaunchKernelGGL(wprep, dim3(144),  dim3(256), 0, stream, w_off, w_conv, wOf, wA);
  hipLaunchKernelGGL(dfuse, dim3(2048), dim3(256), 0, stream, x, wOf, b_off, wA, out);
}

// Round 2
// 142.199 us; speedup vs baseline: 1.2682x; 1.2682x over previous
//
#include <hip/hip_runtime.h>
#include <math.h>

#define HW_   128
#define CIN_  64
#define IMG_  (HW_ * HW_)       // 16384

// 2 output rows x 32 output cols per block
#define TR_    6                // tile rows  [h0-2 .. h0+3]
#define TC_    40               // tile cols  [w0-4 .. w0+35]
#define PIT_   36               // dwords per pixel (64ch bf16 = 32 dw + 4 pad)
                                // MUST be mult of 4: keeps every u32x4 LDS access 16B-aligned
#define TILEDW (TR_ * TC_ * PIT_)   // 8640 dw = 34560 B -> 4 blocks/CU

typedef short    s16x8 __attribute__((ext_vector_type(8)));
typedef float    f32x4 __attribute__((ext_vector_type(4)));
typedef unsigned u32x4 __attribute__((ext_vector_type(4)));

__device__ __forceinline__ short f2bf(float f) {
  union { float f; unsigned i; } v; v.f = f;
  unsigned r = (v.i + 0x7fffu + ((v.i >> 16) & 1u)) >> 16;   // RNE
  return (short)r;
}

#if defined(__has_builtin)
#if __has_builtin(__builtin_amdgcn_cvt_pk_bf16_f32)
#define HAVE_CVT_PK_BF16 1
#endif
#endif

// pack two f32 -> bf16 pair (lo=a, hi=b)
__device__ __forceinline__ unsigned PK2(float a, float b) {
#ifdef HAVE_CVT_PK_BF16
  typedef __bf16 bf16x2_t __attribute__((ext_vector_type(2)));
  union { bf16x2_t v; unsigned u; } cv;
  cv.v = __builtin_amdgcn_cvt_pk_bf16_f32(a, b);
  return cv.u;
#else
  union { float f; unsigned u; } ua, ub; ua.f = a; ub.f = b;
  unsigned ra = ua.u + 0x7fffu + ((ua.u >> 16) & 1u);
  unsigned rb = ub.u + 0x7fffu + ((ub.u >> 16) & 1u);
  return __builtin_amdgcn_perm(rb, ra, 0x07060302u);
#endif
}

// lo channel of packed pair, exact
__device__ __forceinline__ float bfl(unsigned d) {
  union { unsigned u; float f; } v; v.u = d << 16; return v.f;
}
// hi channel, "dirty": low 16 mantissa bits are junk (rel err ~2^-16,
// far below the 2^-9 bf16 repack rounding) -- saves the v_and per dword
__device__ __forceinline__ float bfh(unsigned d) {
  union { unsigned u; float f; } v; v.u = d; return v.f;
}

// ws layout (bytes):
//   [0,     36864)  wOf bf16 [j:9][ks:2][q:4][m:32][i:8]  (A-frag order, m>=27 zero)
//   [36864, 110592) wA  bf16 [j:9][ks:2][q:4][o:64][i:8]  (A-frag order)

__global__ __launch_bounds__(256) void wprep(const float* __restrict__ w_off,
                                             const float* __restrict__ w_conv,
                                             short* __restrict__ wOf,
                                             short* __restrict__ wA) {
  int t = blockIdx.x * 256 + threadIdx.x;
  if (t < 36864) {
    int i = t & 7, o = (t >> 3) & 63, q = (t >> 9) & 3, ks = (t >> 11) & 1, j = t >> 12;
    int c = ks * 32 + q * 8 + i;
    wA[t] = f2bf(w_conv[o * 576 + c * 9 + j]);
  }
  if (t < 18432) {
    int i = t & 7, m = (t >> 3) & 31, q = (t >> 8) & 3, ks = (t >> 10) & 1, j = t >> 11;
    int c = ks * 32 + q * 8 + i;
    wOf[t] = (m < 27) ? f2bf(w_off[(m * 64 + c) * 9 + j]) : (short)0;
  }
}

// Fully fused: stage f32 NCHW -> bf16 NHWC halo tile in LDS (zero-filled OOB,
// one barrier), offset conv (MFMA from tile, no masking needed),
// shuffle-exchange offsets (no barrier),
// LDS-gather deformable sampling + MFMA GEMM (global fallback for |o|>=1).
// Block geometry: 2 output rows x 32 output cols (64 px), 6x40 halo tile.
__global__ __launch_bounds__(256)
__attribute__((amdgpu_waves_per_eu(4)))
void dfuse(const float* __restrict__ x,
           const short* __restrict__ wOf,
           const float* __restrict__ b_off,
           const short* __restrict__ wA,
           float* __restrict__ out) {
  __shared__ __align__(16) unsigned lds_[TILEDW];

  int bi  = blockIdx.x >> 8;
  int tid = blockIdx.x & 255;
  int h0  = (tid >> 2) << 1;       // 0,2,..,126
  int w0  = (tid & 3) << 5;        // 0,32,64,96
  int t   = threadIdx.x;
  int wv  = t >> 6, l = t & 63;
  int col = l & 15, q = l >> 4;
  int px_local = wv * 16 + col;    // 0..63
  int rl  = px_local >> 5;         // local row 0..1
  int cl  = px_local & 31;         // local col 0..31
  int h   = h0 + rl;
  int w   = w0 + cl;
  int p   = h * HW_ + w;

  const float* xB = x + (size_t)bi * (CIN_ * IMG_);

  // ---- stage halo tile: rows h0-2..h0+3, cols w0-4..w0+35, 64 ch bf16 ----
  // unit = (row r, ch-pair cp, col-chunk cc of 4 px); cc fastest => coalesced.
  // OOB image positions stored as ZERO (conv zero-pad + garbage-free phase-3).
  for (int u = t; u < TR_ * 32 * 10; u += 256) {     // 1920 units
    int cc = u % 10;
    int rc = u / 10;
    int cp = rc & 31;
    int r  = rc >> 5;
    int y  = h0 - 2 + r;
    int ys = min(max(y, 0), HW_ - 1);
    int xg0 = w0 - 4 + cc * 4;
    int xs  = min(max(xg0, 0), HW_ - 4);             // stays 16B-aligned
    bool ok = (y >= 0) && (y < HW_) && (xg0 >= 0) && (xg0 < HW_);
    const float* s0 = xB + (2 * cp) * IMG_ + ys * HW_ + xs;
    float4 f0 = *(const float4*)s0;                  // ch 2cp
    float4 f1 = *(const float4*)(s0 + IMG_);         // ch 2cp+1
    int sd = (r * TC_ + cc * 4) * PIT_ + cp;
    lds_[sd]            = ok ? PK2(f0.x, f1.x) : 0u;
    lds_[sd + PIT_]     = ok ? PK2(f0.y, f1.y) : 0u;
    lds_[sd + 2 * PIT_] = ok ? PK2(f0.z, f1.z) : 0u;
    lds_[sd + 3 * PIT_] = ok ? PK2(f0.w, f1.w) : 0u;
  }
  __syncthreads();

  // ---- phase 1: offset conv from tile (tile is zero-padded: no masking) ----
  float oall[32];
  {
    const short* wq = wOf + q * 256 + col * 8;
    f32x4 a0v = {0.f, 0.f, 0.f, 0.f};
    f32x4 a1v = {0.f, 0.f, 0.f, 0.f};
    const unsigned* tb = &lds_[((rl + 2) * TC_ + (cl + 4)) * PIT_ + q * 4];
#pragma unroll
    for (int j = 0; j < 9; ++j) {
      int dy = j / 3 - 1, dx = j % 3 - 1;
      const unsigned* tp = tb + (dy * TC_ + dx) * PIT_;   // compile-time imm
      union { u32x4 u; s16x8 v; } B0, B1;
      B0.u = *(const u32x4*)tp;
      B1.u = *(const u32x4*)(tp + 16);
      const short* wj = wq + j * 2048;
      s16x8 a00 = *(const s16x8*)(wj);
      s16x8 a01 = *(const s16x8*)(wj + 128);
      s16x8 a10 = *(const s16x8*)(wj + 1024);
      s16x8 a11 = *(const s16x8*)(wj + 1024 + 128);
      a0v = __builtin_amdgcn_mfma_f32_16x16x32_bf16(a00, B0.v, a0v, 0, 0, 0);
      a1v = __builtin_amdgcn_mfma_f32_16x16x32_bf16(a01, B0.v, a1v, 0, 0, 0);
      a0v = __builtin_amdgcn_mfma_f32_16x16x32_bf16(a10, B1.v, a0v, 0, 0, 0);
      a1v = __builtin_amdgcn_mfma_f32_16x16x32_bf16(a11, B1.v, a1v, 0, 0, 0);
    }
    // bias + sigmoid by producer lanes, then wave-local shuffle exchange
    float myv[8];
#pragma unroll
    for (int r = 0; r < 4; ++r) myv[r] = a0v[r] + b_off[q * 4 + r];
#pragma unroll
    for (int r = 0; r < 4; ++r) {
      int ch = 16 + q * 4 + r;
      float bo = b_off[min(ch, 26)];
      float v = a1v[r] + bo;
      myv[4 + r] = (ch >= 18) ? (1.f / (1.f + __expf(-v))) : v;
    }
#pragma unroll
    for (int qq = 0; qq < 4; ++qq) {
      int src = qq * 16 + col;
#pragma unroll
      for (int r = 0; r < 4; ++r) {
        oall[qq * 4 + r]      = __shfl(myv[r], src);
        oall[16 + qq * 4 + r] = __shfl(myv[4 + r], src);
      }
    }
  }

  // ---- phase 3: LDS-gather sampling + MFMA GEMM ----
  f32x4 acc[4];
#pragma unroll
  for (int ms = 0; ms < 4; ++ms) acc[ms] = (f32x4){0.f, 0.f, 0.f, 0.f};

  const short* wqA = wA + q * 512 + col * 8;

#pragma unroll
  for (int j = 0; j < 9; ++j) {
    float o1 = oall[j], o2 = oall[9 + j], mk = oall[18 + j];

    float pxf = o1 + (float)(w + (j % 3) - 1);
    float pyf = o2 + (float)(h + (j / 3) - 1);
    float fx = floorf(pxf), fy = floorf(pyf);
    int   x0 = (int)fx,   y0 = (int)fy;
    float ax = pxf - fx, ay = pyf - fy;
    float bx = 1.f - ax, by = 1.f - ay;

    // validity factorizes per-axis: zero the axis weight instead of the product
    bx = (x0 >= 0  && x0 < HW_)     ? bx : 0.f;
    ax = (x0 >= -1 && x0 < HW_ - 1) ? ax : 0.f;
    by = (y0 >= 0  && y0 < HW_)     ? by : 0.f;
    ay = (y0 >= -1 && y0 < HW_ - 1) ? ay : 0.f;
    float bym = by * mk, aym = ay * mk;
    float u00 = bym * bx, u01 = bym * ax;
    float u10 = aym * bx, u11 = aym * ax;

    unsigned F0u[4], F1u[4];
    bool intile = (o1 >= -1.f) && (o1 < 1.f) && (o2 >= -1.f) && (o2 < 1.f);
    if (intile) {
      // in-tile guarantee: r0 in [0,4], c0 in [2,36] -> no clamps; r1=r0+1,
      // c1=c0+1 -> all 8 reads are one base + compile-time immediates.
      // 16B alignment holds: (r0*TC_+c0)*PIT_ + q*4 is a multiple of 4 dw.
      int r0 = y0 - (h0 - 2), c0 = x0 - (w0 - 4);
      const unsigned* t00 = &lds_[(r0 * TC_ + c0) * PIT_ + q * 4];
      u32x4 A00 = *(const u32x4*)(t00);
      u32x4 A01 = *(const u32x4*)(t00 + PIT_);
      u32x4 A10 = *(const u32x4*)(t00 + TC_ * PIT_);
      u32x4 A11 = *(const u32x4*)(t00 + TC_ * PIT_ + PIT_);
      u32x4 B00 = *(const u32x4*)(t00 + 16);
      u32x4 B01 = *(const u32x4*)(t00 + PIT_ + 16);
      u32x4 B10 = *(const u32x4*)(t00 + TC_ * PIT_ + 16);
      u32x4 B11 = *(const u32x4*)(t00 + TC_ * PIT_ + PIT_ + 16);
#pragma unroll
      for (int i = 0; i < 4; ++i) {
        float vlo = fmaf(bfl(A00[i]), u00, fmaf(bfl(A01[i]), u01,
                    fmaf(bfl(A10[i]), u10, bfl(A11[i]) * u11)));
        float vhi = fmaf(bfh(A00[i]), u00, fmaf(bfh(A01[i]), u01,
                    fmaf(bfh(A10[i]), u10, bfh(A11[i]) * u11)));
        F0u[i] = PK2(vlo, vhi);
        float wlo = fmaf(bfl(B00[i]), u00, fmaf(bfl(B01[i]), u01,
                    fmaf(bfl(B10[i]), u10, bfl(B11[i]) * u11)));
        float whi = fmaf(bfh(B00[i]), u00, fmaf(bfh(B01[i]), u01,
                    fmaf(bfh(B10[i]), u10, bfh(B11[i]) * u11)));
        F1u[i] = PK2(wlo, whi);
      }
    } else {
      // rare fallback: gather straight from f32 NCHW x (clamps only here)
      int xc0 = min(max(x0, 0), HW_ - 1), xc1 = min(max(x0 + 1, 0), HW_ - 1);
      int yc0 = min(max(y0, 0), HW_ - 1), yc1 = min(max(y0 + 1, 0), HW_ - 1);
      int g00 = yc0 * HW_ + xc0, g01 = yc0 * HW_ + xc1;
      int g10 = yc1 * HW_ + xc0, g11 = yc1 * HW_ + xc1;
      for (int hB = 0; hB < 2; ++hB) {
        for (int ii = 0; ii < 4; ++ii) {
          int c0i = hB * 32 + q * 8 + 2 * ii;
          const float* pc = xB + c0i * IMG_;
          const float* pd = pc + IMG_;
          float va = u00 * pc[g00] + u01 * pc[g01] + u10 * pc[g10] + u11 * pc[g11];
          float vb = u00 * pd[g00] + u01 * pd[g01] + u10 * pd[g10] + u11 * pd[g11];
          if (hB) F1u[ii] = PK2(va, vb); else F0u[ii] = PK2(va, vb);
        }
      }
    }

    union { unsigned u[4]; s16x8 v; } F0, F1;
#pragma unroll
    for (int i = 0; i < 4; ++i) { F0.u[i] = F0u[i]; F1.u[i] = F1u[i]; }

    const short* wj = wqA + j * 4096;
#pragma unroll
    for (int ms = 0; ms < 4; ++ms) {
      s16x8 a0 = *(const s16x8*)(wj + ms * 128);
      acc[ms] = __builtin_amdgcn_mfma_f32_16x16x32_bf16(a0, F0.v, acc[ms], 0, 0, 0);
    }
#pragma unroll
    for (int ms = 0; ms < 4; ++ms) {
      s16x8 a1 = *(const s16x8*)(wj + 2048 + ms * 128);
      acc[ms] = __builtin_amdgcn_mfma_f32_16x16x32_bf16(a1, F1.v, acc[ms], 0, 0, 0);
    }
  }

  float* op = out + (size_t)bi * (CIN_ * IMG_) + p;
#pragma unroll
  for (int ms = 0; ms < 4; ++ms)
#pragma unroll
    for (int r = 0; r < 4; ++r)
      op[(ms * 16 + q * 4 + r) * IMG_] = acc[ms][r];
}

extern "C" void kernel_launch(void* const* d_in, const int* in_sizes, int n_in,
                              void* d_out, int out_size, void* d_ws, size_t ws_size,
                              hipStream_t stream) {
  const float* x      = (const float*)d_in[0];
  const float* w_off  = (const float*)d_in[1];
  const float* b_off  = (const float*)d_in[2];
  const float* w_conv = (const float*)d_in[3];
  float* out = (float*)d_out;

  char* ws = (char*)d_ws;
  short* wOf = (short*)(ws);
  short* wA  = (short*)(ws + 36864);

  hipLaunchKernelGGL(wprep, dim3(144),  dim3(256), 0, stream, w_off, w_conv, wOf, wA);
  hipLaunchKernelGGL(dfuse, dim3(2048), dim3(256), 0, stream, x, wOf, b_off, wA, out);
}

// Round 3
// 127.909 us; speedup vs baseline: 1.4099x; 1.1117x over previous
//
#include <hip/hip_runtime.h>
#include <math.h>

#define HW_   128
#define CIN_  64
#define IMG_  (HW_ * HW_)       // 16384

// 2 output rows x 32 output cols per block
#define TR_    6                // tile rows  [h0-2 .. h0+3]
#define TC_    40               // tile cols  [w0-4 .. w0+35]
#define PIT_   36               // dwords per pixel (64ch bf16 = 32 dw + 4 pad)
                                // MUST be mult of 4: keeps every u32x4 LDS access 16B-aligned
#define TILEDW (TR_ * TC_ * PIT_)   // 8640 dw = 34560 B -> 4 blocks/CU

typedef short    s16x8 __attribute__((ext_vector_type(8)));
typedef float    f32x4 __attribute__((ext_vector_type(4)));
typedef float    f32x2 __attribute__((ext_vector_type(2)));
typedef unsigned u32x4 __attribute__((ext_vector_type(4)));

__device__ __forceinline__ short f2bf(float f) {
  union { float f; unsigned i; } v; v.f = f;
  unsigned r = (v.i + 0x7fffu + ((v.i >> 16) & 1u)) >> 16;   // RNE
  return (short)r;
}

#if defined(__has_builtin)
#if __has_builtin(__builtin_amdgcn_cvt_pk_bf16_f32)
#define HAVE_CVT_PK_BF16 1
#endif
#endif

// pack two f32 -> bf16 pair (lo=a, hi=b)
__device__ __forceinline__ unsigned PK2(float a, float b) {
#ifdef HAVE_CVT_PK_BF16
  typedef __bf16 bf16x2_t __attribute__((ext_vector_type(2)));
  union { bf16x2_t v; unsigned u; } cv;
  cv.v = __builtin_amdgcn_cvt_pk_bf16_f32(a, b);
  return cv.u;
#else
  union { float f; unsigned u; } ua, ub; ua.f = a; ub.f = b;
  unsigned ra = ua.u + 0x7fffu + ((ua.u >> 16) & 1u);
  unsigned rb = ub.u + 0x7fffu + ((ub.u >> 16) & 1u);
  return __builtin_amdgcn_perm(rb, ra, 0x07060302u);
#endif
}

// dirty-hi f32x2 unpack of a bf16 pair: elem0 exact (d<<16), elem1 keeps the
// junk low 16 mantissa bits (rel err ~2^-16, far below the 2^-9 bf16 repack
// rounding). 1 VALU op per dword; blend chains on f32x2 emit v_pk_fma_f32.
__device__ __forceinline__ f32x2 up2d(unsigned d) {
  union { unsigned u; float f; } lo, hi;
  lo.u = d << 16; hi.u = d;
  return (f32x2){lo.f, hi.f};
}

// ws layout (bytes):
//   [0,     36864)  wOf bf16 [j:9][ks:2][q:4][m:32][i:8]  (A-frag order, m>=27 zero)
//   [36864, 110592) wA  bf16 [j:9][ks:2][q:4][o:64][i:8]  (A-frag order)

__global__ __launch_bounds__(256) void wprep(const float* __restrict__ w_off,
                                             const float* __restrict__ w_conv,
                                             short* __restrict__ wOf,
                                             short* __restrict__ wA) {
  int t = blockIdx.x * 256 + threadIdx.x;
  if (t < 36864) {
    int i = t & 7, o = (t >> 3) & 63, q = (t >> 9) & 3, ks = (t >> 11) & 1, j = t >> 12;
    int c = ks * 32 + q * 8 + i;
    wA[t] = f2bf(w_conv[o * 576 + c * 9 + j]);
  }
  if (t < 18432) {
    int i = t & 7, m = (t >> 3) & 31, q = (t >> 8) & 3, ks = (t >> 10) & 1, j = t >> 11;
    int c = ks * 32 + q * 8 + i;
    wOf[t] = (m < 27) ? f2bf(w_off[(m * 64 + c) * 9 + j]) : (short)0;
  }
}

// Fully fused: stage f32 NCHW -> bf16 NHWC halo tile in LDS (zero-filled OOB,
// one barrier), offset conv (MFMA from tile, no masking needed),
// shuffle-exchange offsets (no barrier),
// LDS-gather deformable sampling + MFMA GEMM (global fallback for |o|>=1).
// Block geometry: 2 output rows x 32 output cols (64 px), 6x40 halo tile.
// XCD swizzle: bi = blockIdx&7 puts each of the 8 images on one XCD
// (round-robin dispatch), so the 3.75x halo re-reads hit that XCD's 4MB L2.
__global__ __launch_bounds__(256)
__attribute__((amdgpu_waves_per_eu(4)))
void dfuse(const float* __restrict__ x,
           const short* __restrict__ wOf,
           const float* __restrict__ b_off,
           const short* __restrict__ wA,
           float* __restrict__ out) {
  __shared__ __align__(16) unsigned lds_[TILEDW];

  int bi  = blockIdx.x & 7;        // XCD-aligned image index
  int tid = blockIdx.x >> 3;       // 0..255 tile within image
  int h0  = (tid >> 2) << 1;       // 0,2,..,126
  int w0  = (tid & 3) << 5;        // 0,32,64,96
  int t   = threadIdx.x;
  int wv  = t >> 6, l = t & 63;
  int col = l & 15, q = l >> 4;
  int px_local = wv * 16 + col;    // 0..63
  int rl  = px_local >> 5;         // local row 0..1
  int cl  = px_local & 31;         // local col 0..31
  int h   = h0 + rl;
  int w   = w0 + cl;
  int p   = h * HW_ + w;

  const float* xB = x + (size_t)bi * (CIN_ * IMG_);

  // ---- stage halo tile: rows h0-2..h0+3, cols w0-4..w0+35, 64 ch bf16 ----
  // unit = (row r, ch-pair cp, col-chunk cc of 4 px); cc fastest => coalesced.
  // OOB image positions stored as ZERO (conv zero-pad + garbage-free phase-3).
  for (int u = t; u < TR_ * 32 * 10; u += 256) {     // 1920 units
    int cc = u % 10;
    int rc = u / 10;
    int cp = rc & 31;
    int r  = rc >> 5;
    int y  = h0 - 2 + r;
    int ys = min(max(y, 0), HW_ - 1);
    int xg0 = w0 - 4 + cc * 4;
    int xs  = min(max(xg0, 0), HW_ - 4);             // stays 16B-aligned
    bool ok = (y >= 0) && (y < HW_) && (xg0 >= 0) && (xg0 < HW_);
    const float* s0 = xB + (2 * cp) * IMG_ + ys * HW_ + xs;
    float4 f0 = *(const float4*)s0;                  // ch 2cp
    float4 f1 = *(const float4*)(s0 + IMG_);         // ch 2cp+1
    int sd = (r * TC_ + cc * 4) * PIT_ + cp;
    lds_[sd]            = ok ? PK2(f0.x, f1.x) : 0u;
    lds_[sd + PIT_]     = ok ? PK2(f0.y, f1.y) : 0u;
    lds_[sd + 2 * PIT_] = ok ? PK2(f0.z, f1.z) : 0u;
    lds_[sd + 3 * PIT_] = ok ? PK2(f0.w, f1.w) : 0u;
  }
  __syncthreads();

  // ---- phase 1: offset conv from tile (tile is zero-padded: no masking) ----
  float oall[32];
  {
    const short* wq = wOf + q * 256 + col * 8;
    f32x4 a0v = {0.f, 0.f, 0.f, 0.f};
    f32x4 a1v = {0.f, 0.f, 0.f, 0.f};
    const unsigned* tb = &lds_[((rl + 2) * TC_ + (cl + 4)) * PIT_ + q * 4];
#pragma unroll
    for (int j = 0; j < 9; ++j) {
      int dy = j / 3 - 1, dx = j % 3 - 1;
      const unsigned* tp = tb + (dy * TC_ + dx) * PIT_;   // compile-time imm
      union { u32x4 u; s16x8 v; } B0, B1;
      B0.u = *(const u32x4*)tp;
      B1.u = *(const u32x4*)(tp + 16);
      const short* wj = wq + j * 2048;
      s16x8 a00 = *(const s16x8*)(wj);
      s16x8 a01 = *(const s16x8*)(wj + 128);
      s16x8 a10 = *(const s16x8*)(wj + 1024);
      s16x8 a11 = *(const s16x8*)(wj + 1024 + 128);
      a0v = __builtin_amdgcn_mfma_f32_16x16x32_bf16(a00, B0.v, a0v, 0, 0, 0);
      a1v = __builtin_amdgcn_mfma_f32_16x16x32_bf16(a01, B0.v, a1v, 0, 0, 0);
      a0v = __builtin_amdgcn_mfma_f32_16x16x32_bf16(a10, B1.v, a0v, 0, 0, 0);
      a1v = __builtin_amdgcn_mfma_f32_16x16x32_bf16(a11, B1.v, a1v, 0, 0, 0);
    }
    // bias + sigmoid by producer lanes, then wave-local shuffle exchange
    float myv[8];
#pragma unroll
    for (int r = 0; r < 4; ++r) myv[r] = a0v[r] + b_off[q * 4 + r];
#pragma unroll
    for (int r = 0; r < 4; ++r) {
      int ch = 16 + q * 4 + r;
      float bo = b_off[min(ch, 26)];
      float v = a1v[r] + bo;
      myv[4 + r] = (ch >= 18) ? (1.f / (1.f + __expf(-v))) : v;
    }
#pragma unroll
    for (int qq = 0; qq < 4; ++qq) {
      int src = qq * 16 + col;
#pragma unroll
      for (int r = 0; r < 4; ++r) {
        oall[qq * 4 + r]      = __shfl(myv[r], src);
        oall[16 + qq * 4 + r] = __shfl(myv[4 + r], src);
      }
    }
  }

  // ---- phase 3: LDS-gather sampling + MFMA GEMM ----
  f32x4 acc[4];
#pragma unroll
  for (int ms = 0; ms < 4; ++ms) acc[ms] = (f32x4){0.f, 0.f, 0.f, 0.f};

  const short* wqA = wA + q * 512 + col * 8;

#pragma unroll
  for (int j = 0; j < 9; ++j) {
    float o1 = oall[j], o2 = oall[9 + j], mk = oall[18 + j];

    float pxf = o1 + (float)(w + (j % 3) - 1);
    float pyf = o2 + (float)(h + (j / 3) - 1);
    float fx = floorf(pxf), fy = floorf(pyf);
    int   x0 = (int)fx,   y0 = (int)fy;
    float ax = pxf - fx, ay = pyf - fy;
    float bx = 1.f - ax, by = 1.f - ay;

    // validity factorizes per-axis: zero the axis weight instead of the product
    bx = (x0 >= 0  && x0 < HW_)     ? bx : 0.f;
    ax = (x0 >= -1 && x0 < HW_ - 1) ? ax : 0.f;
    by = (y0 >= 0  && y0 < HW_)     ? by : 0.f;
    ay = (y0 >= -1 && y0 < HW_ - 1) ? ay : 0.f;
    float bym = by * mk, aym = ay * mk;
    float u00 = bym * bx, u01 = bym * ax;
    float u10 = aym * bx, u11 = aym * ax;
    f32x2 U00 = {u00, u00}, U01 = {u01, u01};
    f32x2 U10 = {u10, u10}, U11 = {u11, u11};

    unsigned F0u[4], F1u[4];
    bool intile = (o1 >= -1.f) && (o1 < 1.f) && (o2 >= -1.f) && (o2 < 1.f);
    if (intile) {
      // in-tile guarantee: r0 in [0,4], c0 in [2,36] -> no clamps; r1=r0+1,
      // c1=c0+1 -> all 8 reads are one base + compile-time immediates.
      // 16B alignment holds: (r0*TC_+c0)*PIT_ + q*4 is a multiple of 4 dw.
      int r0 = y0 - (h0 - 2), c0 = x0 - (w0 - 4);
      const unsigned* t00 = &lds_[(r0 * TC_ + c0) * PIT_ + q * 4];
      u32x4 A00 = *(const u32x4*)(t00);
      u32x4 A01 = *(const u32x4*)(t00 + PIT_);
      u32x4 A10 = *(const u32x4*)(t00 + TC_ * PIT_);
      u32x4 A11 = *(const u32x4*)(t00 + TC_ * PIT_ + PIT_);
      u32x4 B00 = *(const u32x4*)(t00 + 16);
      u32x4 B01 = *(const u32x4*)(t00 + PIT_ + 16);
      u32x4 B10 = *(const u32x4*)(t00 + TC_ * PIT_ + 16);
      u32x4 B11 = *(const u32x4*)(t00 + TC_ * PIT_ + PIT_ + 16);
#pragma unroll
      for (int i = 0; i < 4; ++i) {
        f32x2 v0 = up2d(A00[i]) * U00 + up2d(A01[i]) * U01
                 + up2d(A10[i]) * U10 + up2d(A11[i]) * U11;   // v_pk_fma_f32
        F0u[i] = PK2(v0.x, v0.y);
        f32x2 v1 = up2d(B00[i]) * U00 + up2d(B01[i]) * U01
                 + up2d(B10[i]) * U10 + up2d(B11[i]) * U11;
        F1u[i] = PK2(v1.x, v1.y);
      }
    } else {
      // rare fallback: gather straight from f32 NCHW x (clamps only here)
      int xc0 = min(max(x0, 0), HW_ - 1), xc1 = min(max(x0 + 1, 0), HW_ - 1);
      int yc0 = min(max(y0, 0), HW_ - 1), yc1 = min(max(y0 + 1, 0), HW_ - 1);
      int g00 = yc0 * HW_ + xc0, g01 = yc0 * HW_ + xc1;
      int g10 = yc1 * HW_ + xc0, g11 = yc1 * HW_ + xc1;
      for (int hB = 0; hB < 2; ++hB) {
        for (int ii = 0; ii < 4; ++ii) {
          int c0i = hB * 32 + q * 8 + 2 * ii;
          const float* pc = xB + c0i * IMG_;
          const float* pd = pc + IMG_;
          float va = u00 * pc[g00] + u01 * pc[g01] + u10 * pc[g10] + u11 * pc[g11];
          float vb = u00 * pd[g00] + u01 * pd[g01] + u10 * pd[g10] + u11 * pd[g11];
          if (hB) F1u[ii] = PK2(va, vb); else F0u[ii] = PK2(va, vb);
        }
      }
    }

    union { unsigned u[4]; s16x8 v; } F0, F1;
#pragma unroll
    for (int i = 0; i < 4; ++i) { F0.u[i] = F0u[i]; F1.u[i] = F1u[i]; }

    const short* wj = wqA + j * 4096;
#pragma unroll
    for (int ms = 0; ms < 4; ++ms) {
      s16x8 a0 = *(const s16x8*)(wj + ms * 128);
      acc[ms] = __builtin_amdgcn_mfma_f32_16x16x32_bf16(a0, F0.v, acc[ms], 0, 0, 0);
    }
#pragma unroll
    for (int ms = 0; ms < 4; ++ms) {
      s16x8 a1 = *(const s16x8*)(wj + 2048 + ms * 128);
      acc[ms] = __builtin_amdgcn_mfma_f32_16x16x32_bf16(a1, F1.v, acc[ms], 0, 0, 0);
    }
  }

  float* op = out + (size_t)bi * (CIN_ * IMG_) + p;
#pragma unroll
  for (int ms = 0; ms < 4; ++ms)
#pragma unroll
    for (int r = 0; r < 4; ++r)
      op[(ms * 16 + q * 4 + r) * IMG_] = acc[ms][r];
}

extern "C" void kernel_launch(void* const* d_in, const int* in_sizes, int n_in,
                              void* d_out, int out_size, void* d_ws, size_t ws_size,
                              hipStream_t stream) {
  const float* x      = (const float*)d_in[0];
  const float* w_off  = (const float*)d_in[1];
  const float* b_off  = (const float*)d_in[2];
  const float* w_conv = (const float*)d_in[3];
  float* out = (float*)d_out;

  char* ws = (char*)d_ws;
  short* wOf = (short*)(ws);
  short* wA  = (short*)(ws + 36864);

  hipLaunchKernelGGL(wprep, dim3(144),  dim3(256), 0, stream, w_off, w_conv, wOf, wA);
  hipLaunchKernelGGL(dfuse, dim3(2048), dim3(256), 0, stream, x, wOf, b_off, wA, out);
}